// Round 10
// baseline (388.773 us; speedup 1.0000x reference)
//
#include <hip/hip_runtime.h>
#include <hip/hip_bf16.h>

#define B_    2
#define N_    4096
#define NV_   32768
#define HID_  128
#define XD_   128
#define YD_   128
#define ZD_   16
#define PLANE (XD_*YD_*ZD_)      // 262144
#define LOCS  (B_*PLANE)         // 524288
#define STEP  (100.0f/15.0f)
#define KS    4                  // K-split factor (k-chunk = 1024)
#define VBL   160                // v-blocks per seg
#define NFUSE (2*VBL*KS)         // 1280 fuse items
#define NZERO 512                // zero-writer blocks (512*256 quads = LOCS/4)
#define L2E   1.4426950408889634f

typedef __attribute__((ext_vector_type(8)))  short short8;
typedef __attribute__((ext_vector_type(16))) float f32x16;
typedef __attribute__((ext_vector_type(4)))  float fv4;

__device__ __forceinline__ float anchor_s(int i) {   // log2e-scaled anchor coord
    return fmaf((float)i, STEP * L2E, -50.0f * L2E);
}
__device__ __forceinline__ float fexp2(float x) {
    float r; asm("v_exp_f32 %0, %1" : "=v"(r) : "v"(x)); return r;
}
__device__ __forceinline__ unsigned short f2bf(float x) {
    unsigned u = __float_as_uint(x);
    return (unsigned short)((u + 0x7fffu + ((u >> 16) & 1u)) >> 16);
}
__device__ __forceinline__ void gload16(const void* g, void* l) {
    __builtin_amdgcn_global_load_lds(
        (const __attribute__((address_space(1))) unsigned int*)g,
        (__attribute__((address_space(3))) unsigned int*)l, 16, 0, 0);
}

// ---------------- MLP: 8 rows/block, 4-way ILP on W2 loop ----------------
__global__ __launch_bounds__(256) void mlp_kernel(
    const float* __restrict__ pos, const float* __restrict__ scl,
    const float* __restrict__ rot, const float* __restrict__ opa,
    const float* __restrict__ W1,  const float* __restrict__ b1,
    const float* __restrict__ W2,  const float* __restrict__ b2,
    unsigned short* __restrict__ xwT)
{
    int tid = threadIdx.x;
    int j  = tid & 127;
    int rg = tid >> 7;
    int r0 = blockIdx.x * 8;
    __shared__ float sin_[8][11];
    __shared__ float h[8][HID_];
    if (tid < 88) {
        int rr = tid / 11, c = tid - rr*11;
        int r = r0 + rr;
        float val;
        if (c < 3)       val = pos[r*3 + c];
        else if (c < 6)  val = scl[r*3 + (c-3)];
        else if (c < 10) val = rot[r*4 + (c-6)];
        else             val = opa[r];
        sin_[rr][c] = val;
    }
    __syncthreads();
    float bb1 = b1[j];
    #pragma unroll
    for (int q = 0; q < 4; ++q) {
        int rr = rg*4 + q;
        float a = bb1;
        #pragma unroll
        for (int i = 0; i < 11; ++i) a = fmaf(sin_[rr][i], W1[i*HID_ + j], a);
        h[rr][j] = fmaxf(a, 0.0f);
    }
    __syncthreads();
    float bb2 = b2[j];
    float o0 = bb2, o1 = bb2, o2 = bb2, o3 = bb2;
    #pragma unroll 4
    for (int k = 0; k < HID_; ++k) {
        float w2 = W2[k*HID_ + j];
        int rb = rg*4;
        o0 = fmaf(h[rb+0][k], w2, o0);
        o1 = fmaf(h[rb+1][k], w2, o1);
        o2 = fmaf(h[rb+2][k], w2, o2);
        o3 = fmaf(h[rb+3][k], w2, o3);
    }
    float o[4] = {o0, o1, o2, o3};
    #pragma unroll
    for (int q = 0; q < 4; ++q) {
        int r = r0 + rg*4 + q;
        int b = r >> 12, n = r & 4095;
        xwT[((size_t)(b*HID_ + j))*N_ + n] = f2bf(o[q]);
    }
}

// ------------- pass A (+ scatter folded in): per-v (m_l2e, 1/l), 8 lanes/v -------------
__global__ __launch_bounds__(256) void ml_kernel(
    const int* __restrict__ vc, float2* __restrict__ ml,
    int* __restrict__ map, int* __restrict__ cnt, int* __restrict__ vlist)
{
    int gid = blockIdx.x * 256 + threadIdx.x;
    int v = gid >> 3, sub = gid & 7;
    int4 c = ((const int4*)vc)[v];

    if (sub == 0) {
        int loc = ((c.x*XD_ + c.y)*YD_ + c.z)*ZD_ + c.w;
        atomicMax(&map[loc], v);
        int lane = threadIdx.x & 63;
        unsigned long long act = __ballot(1);
        unsigned long long m1 = __ballot(c.x != 0);
        unsigned long long mymask = c.x ? m1 : (act & ~m1);
        int leader = (int)__ffsll(mymask) - 1;
        int total  = __popcll(mymask);
        int rank   = __popcll(mymask & ((1ull << lane) - 1ull));
        int base = 0;
        if (lane == leader) base = atomicAdd(&cnt[c.x], total);
        base = __shfl(base, leader);
        vlist[c.x*NV_ + base + rank] = v;
    }

    float vx = (float)c.y * L2E, vy = (float)c.z * L2E, vz = (float)c.w * L2E;
    float dz2_[16];
    float mindz2 = 1e30f;
    #pragma unroll 16
    for (int iz = 0; iz < 16; ++iz) {
        float t = vz - anchor_s(iz); dz2_[iz] = t*t;
        mindz2 = fminf(mindz2, dz2_[iz]);
    }
    float dxa = vx - anchor_s(sub*2), dxb = vx - anchor_s(sub*2 + 1);
    float dx2_[2] = {dxa*dxa, dxb*dxb};

    float md[4] = {1e30f, 1e30f, 1e30f, 1e30f};
    #pragma unroll
    for (int i = 0; i < 2; ++i) {
        for (int iy = 0; iy < 16; ++iy) {
            float dy = vy - anchor_s(iy);
            float bxy = fmaf(dy, dy, dx2_[i]);
            #pragma unroll 16
            for (int iz = 0; iz < 16; ++iz)
                md[iz & 3] = fminf(md[iz & 3], bxy + dz2_[iz]);
        }
    }
    float m2v = fminf(fminf(md[0], md[1]), fminf(md[2], md[3]));
    #pragma unroll
    for (int off = 1; off < 8; off <<= 1) m2v = fminf(m2v, __shfl_xor(m2v, off));
    float m = sqrtf(m2v);

    float lim = m + 34.0f;
    float lim2 = lim * lim;
    float la = 0.f, lb = 0.f;
    #pragma unroll
    for (int i = 0; i < 2; ++i) {
        for (int iy = 0; iy < 16; ++iy) {
            float dy = vy - anchor_s(iy);
            float bxy = fmaf(dy, dy, dx2_[i]);
            if (bxy + mindz2 <= lim2) {
                #pragma unroll 8
                for (int iz = 0; iz < 16; iz += 2) {
                    la += fexp2(m - sqrtf(bxy + dz2_[iz]));
                    lb += fexp2(m - sqrtf(bxy + dz2_[iz+1]));
                }
            }
        }
    }
    float l = la + lb;
    #pragma unroll
    for (int off = 1; off < 8; off <<= 1) l += __shfl_xor(l, off);
    if (sub == 0) ml[v] = make_float2(m, 1.0f / l);
}

// ------------- fuse + zero-writer, interleaved in one grid -------------
// bid%7 in {3,6} -> zero-writer block (writes all-invalid quads of d_out).
// Others -> fuse item (identical to R8's proven fuse body).
__global__ __launch_bounds__(256) void fusezero_kernel(
    const unsigned short* __restrict__ xwT, const float2* __restrict__ ml,
    const int* __restrict__ vc,   const int* __restrict__ vlist,
    const int* __restrict__ cnt,  float* __restrict__ fused_p,
    const int* __restrict__ map,  float* __restrict__ out)
{
    int bid = blockIdx.x;
    int g = bid / 7, r = bid - g*7;
    int tid = threadIdx.x;

    if (r == 3 || r == 6) {
        // ================= zero-writer: 256 quads per block =================
        int zidx = g*2 + (r == 6 ? 1 : 0);
        int q = zidx*256 + tid;
        int4 vv = ((const int4*)map)[q];
        if ((vv.x & vv.y & vv.z & vv.w) < 0) {   // all four locs invalid
            int loc0 = q << 2;
            int b   = loc0 >> 18;
            int rem = loc0 & (PLANE - 1);
            size_t obase = ((size_t)b * HID_) * PLANE + rem;
            const fv4 z4 = (fv4)(0.f);
            #pragma unroll 4
            for (int ch = 0; ch < HID_; ++ch)
                __builtin_nontemporal_store(z4, (fv4*)&out[obase + (size_t)ch * PLANE]);
        }
        return;
    }

    // ================= fuse item =================
    const int fcnt_[7] = {0, 1, 2, 3, 3, 4, 5};
    int item = g*5 + fcnt_[r];

    int ks_  = item & (KS-1);
    int rest = item >> 2;
    int seg  = (rest >= VBL) ? 1 : 0;
    int bi   = rest - seg*VBL;
    int count = cnt[seg];
    int vbase = bi * 128;
    if (vbase >= count) return;
    int nv = min(128, count - vbase);
    int k0 = ks_ * (N_/KS);

    __shared__ __align__(16) unsigned char sXT[2][16384];
    __shared__ int svid[128];

    int w  = tid >> 6, l = tid & 63;
    int h  = l >> 5;
    int cl = l & 31;

    if (tid < 128) svid[tid] = (tid < nv) ? vlist[seg*NV_ + vbase + tid] : -1;

    int vloc = w*32 + cl;
    float pml = -1e30f, pvx = 0.f, pvy = 0.f;
    float dz2h[8];
    #pragma unroll
    for (int z = 0; z < 8; ++z) dz2h[z] = 0.f;
    if (vloc < nv) {
        int vid = vlist[seg*NV_ + vbase + vloc];
        int4 cc = ((const int4*)vc)[vid];
        pvx = (float)cc.y * L2E; pvy = (float)cc.z * L2E;
        float pvz = (float)cc.w * L2E;
        pml = ml[vid].x;
        #pragma unroll
        for (int z = 0; z < 8; ++z) { float t0 = pvz - anchor_s(h*8 + z); dz2h[z] = t0*t0; }
    }

    int d0s  = w*32 + (l >> 3);
    int blkX = (l & 7) ^ ((l >> 3) & 7);
    const unsigned short* sb = xwT + (size_t)(seg*HID_ + d0s)*N_ + blkX*8 + k0;

    f32x16 acc[4];
    #pragma unroll
    for (int i = 0; i < 4; ++i) acc[i] = (f32x16)(0.f);

    {
        char* ldsb = (char*)&sXT[0][0] + w*4096;
        #pragma unroll
        for (int i = 0; i < 4; ++i)
            gload16(sb + (size_t)i*8*N_, ldsb + i*1024);
    }

    const int TILES = (N_/KS)/64;    // 16
    for (int t = 0; t < TILES; ++t) {
        int cur = t & 1;
        unsigned pk_[4][4];
        int nb = k0 + t*64;
        #pragma unroll
        for (int kss = 0; kss < 4; ++kss) {
            int kg = nb + kss*16;
            float ax = anchor_s(kg >> 8);
            float ay = anchor_s((kg >> 4) & 15);
            float dx = pvx - ax, dy = pvy - ay;
            float bxy = fmaf(dx, dx, dy*dy);
            #pragma unroll
            for (int jj = 0; jj < 4; ++jj) {
                float dA = sqrtf(bxy + dz2h[2*jj]);
                float dB = sqrtf(bxy + dz2h[2*jj + 1]);
                float p0 = fexp2(pml - dA);
                float p1 = fexp2(pml - dB);
                asm("v_cvt_pk_bf16_f32 %0, %1, %2" : "=v"(pk_[kss][jj]) : "v"(p0), "v"(p1));
            }
        }
        __syncthreads();              // buf[cur] staged (vmcnt drained); buf[cur^1] free
        if (t + 1 < TILES) {
            char* ldsb = (char*)&sXT[cur^1][0] + w*4096;
            #pragma unroll
            for (int i = 0; i < 4; ++i)
                gload16(sb + (size_t)i*8*N_ + (t+1)*64, ldsb + i*1024);
        }
        #pragma unroll
        for (int kss = 0; kss < 4; ++kss) {
            union { uint4 q; short8 s; } u8;
            u8.q = make_uint4(pk_[kss][0], pk_[kss][1], pk_[kss][2], pk_[kss][3]);
            short8 af = u8.s;
            #pragma unroll
            for (int df = 0; df < 4; ++df) {
                int row = df*32 + cl;
                int blk = (kss*2 + h) ^ (row & 7);
                short8 bf = *(const short8*)&sXT[cur][row*128 + blk*16];
                acc[df] = __builtin_amdgcn_mfma_f32_32x32x16_bf16(af, bf, acc[df], 0, 0, 0);
            }
        }
    }

    // epilogue: cacheable stores (out_valid gathers these from L3)
    float* fp = fused_p + (size_t)ks_ * NV_ * HID_;
    #pragma unroll
    for (int df = 0; df < 4; ++df) {
        int dcol = df*32 + cl;
        #pragma unroll
        for (int reg = 0; reg < 16; ++reg) {
            int vrow = w*32 + (reg & 3) + 8*(reg >> 2) + 4*h;
            int sv = svid[vrow];
            if (sv >= 0) fp[(size_t)sv*HID_ + dcol] = acc[df][reg];
        }
    }
}

// ------------- out_valid: quads with >=1 valid loc; sums 4 partials, scales by 1/l -------------
__global__ __launch_bounds__(256) void outv_kernel(
    const int* __restrict__ map, const float* __restrict__ fused_p,
    const float2* __restrict__ ml, float* __restrict__ out)
{
    int q = blockIdx.x * 256 + threadIdx.x;     // LOCS/4 threads total
    int4 vv = ((const int4*)map)[q];
    if ((vv.x & vv.y & vv.z & vv.w) < 0) return;   // handled by zero-writer

    int loc0 = q << 2;
    int b   = loc0 >> 18;
    int rem = loc0 & (PLANE - 1);
    size_t obase = ((size_t)b * HID_) * PLANE + rem;
    const size_t S4 = (size_t)NV_ * HID_ / 4;
    const fv4* P = (const fv4*)fused_p;

    int   va[4] = {vv.x, vv.y, vv.z, vv.w};
    float il[4];
    const fv4* rp[4];
    #pragma unroll
    for (int k = 0; k < 4; ++k) {
        il[k] = (va[k] >= 0) ? ml[va[k]].y : 0.0f;
        rp[k] = P + (size_t)(va[k] >= 0 ? va[k] : 0) * 32;
    }

    for (int chb = 0; chb < 32; ++chb) {
        fv4 vals[4];
        #pragma unroll
        for (int k = 0; k < 4; ++k) {
            fv4 s = (fv4)(0.f);
            if (va[k] >= 0) {
                fv4 a = rp[k][chb];
                fv4 bq = rp[k][chb + S4];
                fv4 cq = rp[k][chb + 2*S4];
                fv4 dq = rp[k][chb + 3*S4];
                s = (a + bq + cq + dq) * il[k];
            }
            vals[k] = s;
        }
        fv4 o0 = {vals[0].x, vals[1].x, vals[2].x, vals[3].x};
        fv4 o1 = {vals[0].y, vals[1].y, vals[2].y, vals[3].y};
        fv4 o2 = {vals[0].z, vals[1].z, vals[2].z, vals[3].z};
        fv4 o3 = {vals[0].w, vals[1].w, vals[2].w, vals[3].w};
        __builtin_nontemporal_store(o0, (fv4*)&out[obase + (size_t)(chb*4 + 0) * PLANE]);
        __builtin_nontemporal_store(o1, (fv4*)&out[obase + (size_t)(chb*4 + 1) * PLANE]);
        __builtin_nontemporal_store(o2, (fv4*)&out[obase + (size_t)(chb*4 + 2) * PLANE]);
        __builtin_nontemporal_store(o3, (fv4*)&out[obase + (size_t)(chb*4 + 3) * PLANE]);
    }
}

extern "C" void kernel_launch(void* const* d_in, const int* in_sizes, int n_in,
                              void* d_out, int out_size, void* d_ws, size_t ws_size,
                              hipStream_t stream) {
    const float* pos = (const float*)d_in[0];
    const float* scl = (const float*)d_in[1];
    const float* rot = (const float*)d_in[2];
    const float* opa = (const float*)d_in[3];
    const float* W1  = (const float*)d_in[4];
    const float* b1  = (const float*)d_in[5];
    const float* W2  = (const float*)d_in[6];
    const float* b2  = (const float*)d_in[7];
    const int*   vc  = (const int*)d_in[8];
    float* out = (float*)d_out;

    char* ws = (char*)d_ws;
    unsigned short* xwT = (unsigned short*)(ws);        // 2 MB
    float2* ml      = (float2*)(ws + (2u<<20));         // 256 KB
    float*  fused_p = (float*) (ws + (4u<<20));         // 64 MB
    int*    map     = (int*)   (ws + (68u<<20));        // 2 MB
    int*    vlist   = (int*)   (ws + (70u<<20));        // 256 KB
    int*    cnt     = (int*)   (ws + (71u<<20));        // 8 B

    hipMemsetAsync(map, 0xFF, LOCS*sizeof(int), stream);
    hipMemsetAsync(cnt, 0, 2*sizeof(int), stream);

    mlp_kernel<<<(B_*N_)/8, 256, 0, stream>>>(pos, scl, rot, opa, W1, b1, W2, b2, xwT);
    ml_kernel<<<(NV_*8)/256, 256, 0, stream>>>(vc, ml, map, cnt, vlist);
    fusezero_kernel<<<NFUSE + NZERO, 256, 0, stream>>>(xwT, ml, vc, vlist, cnt,
                                                       fused_p, map, out);
    outv_kernel<<<LOCS/(256*4), 256, 0, stream>>>(map, fused_p, ml, out);
}